// Round 8
// baseline (1446.929 us; speedup 1.0000x reference)
//
#include <hip/hip_runtime.h>
#include <stdint.h>

typedef unsigned short u16;
typedef __attribute__((ext_vector_type(8))) __bf16 bf16x8;
typedef __attribute__((ext_vector_type(8))) u16 u16x8;
typedef __attribute__((ext_vector_type(4))) float f32x4;

#define T_LEN 2048
#define NB 16

__device__ __forceinline__ u16 f2bf(float f){
  uint32_t x = __builtin_bit_cast(uint32_t, f);
  x += 0x7FFFu + ((x >> 16) & 1u);
  return (u16)(x >> 16);
}

// joint -> (body part, index within part, part length)
__constant__ int c_part[17] = {1,2,3,1,1,4,4,5,5,2,2,3,3,0,0,0,0};
__constant__ int c_pidx[17] = {0,0,0,1,2,0,1,0,1,1,2,1,2,0,1,2,3};
__constant__ int c_plen[17] = {3,3,3,3,3,2,2,2,2,3,3,3,3,4,4,4,4};

// Device-scope grid barrier (generation counter). bar[0]=count, bar[1]=gen.
// Requires all blocks co-resident: grid 1024, __launch_bounds__(256,4).
__device__ __forceinline__ void grid_barrier(int* bar, int nblk){
  __syncthreads();
  if (threadIdx.x == 0){
    __threadfence();
    int g = __hip_atomic_load(bar + 1, __ATOMIC_RELAXED, __HIP_MEMORY_SCOPE_AGENT);
    int v = __hip_atomic_fetch_add(bar, 1, __ATOMIC_ACQ_REL, __HIP_MEMORY_SCOPE_AGENT);
    if (v == nblk - 1){
      __hip_atomic_store(bar, 0, __ATOMIC_RELAXED, __HIP_MEMORY_SCOPE_AGENT);
      __hip_atomic_store(bar + 1, g + 1, __ATOMIC_RELEASE, __HIP_MEMORY_SCOPE_AGENT);
    } else {
      while (__hip_atomic_load(bar + 1, __ATOMIC_ACQUIRE, __HIP_MEMORY_SCOPE_AGENT) == g)
        __builtin_amdgcn_s_sleep(2);
    }
    __threadfence();
  }
  __syncthreads();
}

// ---- mega: entire pipeline in one persistent kernel, 4 phases + 3 barriers.
// P0: conv_poses (7168 vb) + prep_A (1454 vb)        -> X0, W*e/W*eT, W4f, biases
// P1: W32/W32ind (14196 vb) + W1f/W2f/W3f reindex    -> (15708 vb total)
// P2: prep_C composed Wc hi/lo + biasC (4705 vb)
// P3: fused_main (1056 vb): 2-edge MFMA fixup + composed interior GEMM
__launch_bounds__(256, 4)
__global__ void mega(
  const float* __restrict__ poses, const float* __restrict__ A1, const float* __restrict__ A2,
  const float* __restrict__ w1, const float* __restrict__ b1, const float* __restrict__ g1,
  const float* __restrict__ be1, const float* __restrict__ m1, const float* __restrict__ v1,
  const float* __restrict__ w2, const float* __restrict__ b2, const float* __restrict__ g2,
  const float* __restrict__ be2, const float* __restrict__ m2, const float* __restrict__ v2,
  const float* __restrict__ w3, const float* __restrict__ b3, const float* __restrict__ g3,
  const float* __restrict__ be3, const float* __restrict__ m3, const float* __restrict__ v3,
  const float* __restrict__ w4, const float* __restrict__ b4, const float* __restrict__ g4,
  const float* __restrict__ be4, const float* __restrict__ m4, const float* __restrict__ v4,
  u16* __restrict__ X0,
  float* __restrict__ W1e, float* __restrict__ W1eT,
  float* __restrict__ W2e, float* __restrict__ W2eT,
  float* __restrict__ W3e, u16* __restrict__ W4f,
  float* __restrict__ b1f, float* __restrict__ b2f, float* __restrict__ b3f, float* __restrict__ b4f,
  float* __restrict__ W32, float* __restrict__ W32i,
  u16* __restrict__ WcfH, u16* __restrict__ WcfL, float* __restrict__ biasC,
  u16* __restrict__ W1f, u16* __restrict__ W2f, u16* __restrict__ W3f,
  float* __restrict__ out, int* bar)
{
  __shared__ __align__(16) u16 patch[69 * 56];
  __shared__ __align__(16) u16 X3L[48 * 16];
  __shared__ __align__(16) u16 xs [25 * 56];
  __shared__ __align__(16) u16 X1s[25 * 272];
  __shared__ __align__(16) u16 X2s[21 * 96];
  __shared__ __align__(16) u16 X3s[19 * 16];

  const int nblk = gridDim.x;
  const int tid  = threadIdx.x;
  const int lane = tid & 63;
  const int h    = tid >> 6;
  const int q    = lane >> 4;
  const int l15  = lane & 15;

  // ================= Phase 0: conv_poses + prep_A =================
  for (int vb = blockIdx.x; vb < 8622; vb += nblk){
    if (vb < 7168){
      int e = vb * 256 + tid;
      int row = e / 56, c = e - row * 56;
      u16 v = 0;
      if (c < 51) v = f2bf(poses[row * 51 + c]);
      X0[e] = v;
    } else {
      int bid = vb - 7168;                       // < 1454
      if (bid < 488){
        int idx = bid * 256 + tid;
        if (idx < 124848){
          int p = idx / 459, rem = idx - p * 459;
          int d1 = rem / 51, u = rem - d1 * 51;
          int c = p / 17, w = p - c * 17;
          int uj = u / 3, ci = u - uj * 3;
          float val = 0.f;
          for (int kk = 0; kk < 5; ++kk)
            for (int dv = 0; dv < 5; ++dv){
              int v = uj - dv + 2;
              if (v >= 0 && v < 17)
                val += w1[(kk*16 + c)*135 + ci*45 + d1*5 + dv] * A1[kk*289 + v*17 + w];
            }
          val *= g1[p] * rsqrtf(v1[p] + 1e-5f);
          W1e[idx] = val;
          W1eT[(d1*51 + u)*272 + p] = val;
        }
      } else if (bid < 1406){
        int idx = (bid - 488) * 256 + tid;       // < 235008 exact
        int o = idx / 2448, rem = idx - o * 2448;
        int d2 = rem / 272, pp = rem - d2 * 272;
        int c2 = o / 6, w2i = o - c2 * 6;
        int f = pp / 17, J = pp - f * 17;
        int pt = c_part[J];
        int ci = f * c_plen[J] + c_pidx[J];
        float val = 0.f;
        for (int kk = 0; kk < 5; ++kk)
          for (int dv = 0; dv < 3; ++dv){
            int v = pt - dv + 1;
            if (v >= 0 && v < 6)
              val += w2[(kk*16 + c2)*1728 + ci*27 + d2*3 + dv] * A2[kk*36 + v*6 + w2i];
          }
        val *= g2[o] * rsqrtf(v2[o] + 1e-5f);
        W2e[idx] = val;
        W2eT[(d2*272 + pp)*96 + o] = val;
      } else if (bid < 1436){
        int idx = (bid - 1406) * 256 + tid;      // < 7680 exact
        int qq = idx / 480, rem = idx - qq * 480;
        int d3 = rem / 96, o = rem - d3 * 96;
        float s = g3[qq] * rsqrtf(v3[qq] + 1e-5f);
        W3e[idx] = s * w3[qq*480 + o*5 + d3];
      } else if (bid < 1452){
        int i2 = (bid - 1436) * 256 + tid;       // < 4096 exact
        int cw = i2 >> 6, kp = i2 & 63;
        int dt = kp >> 4, ch = kp & 15;
        float val = 0.f;
        if (dt < 3){
          float s = g4[cw] * rsqrtf(v4[cw] + 1e-5f);
          val = s * w4[cw*48 + ch*3 + dt];
        }
        int mt = cw >> 4, r = cw & 15, ks = kp >> 5, kq = kp & 31;
        W4f[(ks*4 + mt)*512 + ((kq>>3)*16 + r)*8 + (kq&7)] = f2bf(val);
      } else {
        int t2 = (bid - 1452) * 256 + tid;       // < 512, 448 used
        if (t2 < 272){
          int c = t2 / 17, w = t2 - c * 17;
          float beff = 0.f;
          for (int kk = 0; kk < 5; ++kk){
            float rs = 0.f;
            for (int v = 0; v < 17; ++v) rs += A1[kk*289 + v*17 + w];
            beff += b1[kk*16 + c] * rs;
          }
          float s = g1[t2] * rsqrtf(v1[t2] + 1e-5f);
          b1f[t2] = s * (beff - m1[t2]) + be1[t2];
        } else if (t2 < 368){
          int cw = t2 - 272;
          int c = cw / 6, w = cw - c * 6;
          float beff = 0.f;
          for (int kk = 0; kk < 5; ++kk){
            float rs = 0.f;
            for (int v = 0; v < 6; ++v) rs += A2[kk*36 + v*6 + w];
            beff += b2[kk*16 + c] * rs;
          }
          float s = g2[cw] * rsqrtf(v2[cw] + 1e-5f);
          b2f[cw] = s * (beff - m2[cw]) + be2[cw];
        } else if (t2 < 384){
          int o = t2 - 368;
          float s = g3[o] * rsqrtf(v3[o] + 1e-5f);
          b3f[o] = s * (b3[o] - m3[o]) + be3[o];
        } else if (t2 < 448){
          int o = t2 - 384;
          float s = g4[o] * rsqrtf(v4[o] + 1e-5f);
          b4f[o] = s * (b4[o] - m4[o]) + be4[o];
        }
      }
    }
  }
  grid_barrier(bar, nblk);

  // ================= Phase 1: W32 composition + fragment reindex =================
  for (int vb = blockIdx.x; vb < 15708; vb += nblk){
    if (vb < 14144){
      int wid = vb * 4 + h;              // < 56576
      int b = wid / 272, p = wid - b * 272;
      int qq = b / 13, d23 = b - qq * 13;
      float accl = 0.f;
      for (int d3 = 0; d3 < 5; ++d3){
        int d2 = d23 - d3;
        if (d2 < 0 || d2 >= 9) continue;
        const float* w3r = W3e + qq*480 + d3*96;
        const float* w2r = W2eT + (d2*272 + p)*96;
#pragma unroll
        for (int j = 0; j < 2; ++j){
          int o = lane + j*64;
          if (o < 96) accl += w3r[o] * w2r[o];
        }
      }
      for (int m = 32; m > 0; m >>= 1) accl += __shfl_xor(accl, m);
      if (lane == 0) W32[b*272 + p] = accl;
    } else if (vb < 14196){
      int wid = (vb - 14144) * 4 + h;    // < 208
      int qq = wid / 13, d23 = wid - qq * 13;
      float accl = 0.f;
      int d3 = d23 - 4;
      if (d3 >= 0 && d3 < 5){
        const float* w3r = W3e + qq*480 + d3*96;
#pragma unroll
        for (int j = 0; j < 2; ++j){
          int o = lane + j*64;
          if (o < 96) accl += w3r[o] * b2f[o];
        }
      }
      for (int m = 32; m > 0; m >>= 1) accl += __shfl_xor(accl, m);
      if (lane == 0){
        if (d23 == 6) accl += b3f[qq];
        W32i[wid] = accl;
      }
    } else if (vb < 14740){
      int idx = (vb - 14196) * 256 + tid;   // < 139264 exact
      int cw = idx >> 9, kp = idx & 511;
      int dt = kp / 56, u = kp - dt * 56;
      float val = (dt < 9 && u < 51) ? W1e[(cw*9 + dt)*51 + u] : 0.f;
      int mt = cw >> 4, r = cw & 15, ks = kp >> 5, kq = kp & 31;
      W1f[(ks*17 + mt)*512 + ((kq>>3)*16 + r)*8 + (kq&7)] = f2bf(val);
    } else if (vb < 15676){
      int idx = (vb - 14740) * 256 + tid;   // < 239616 exact
      int cw = idx / 2496, kp = idx - cw * 2496;
      int dt = kp / 272, pp = kp - dt * 272;
      float val = (dt < 9) ? W2e[(cw*9 + dt)*272 + pp] : 0.f;
      int mt = cw >> 4, r = cw & 15, ks = kp >> 5, kq = kp & 31;
      W2f[(ks*6 + mt)*512 + ((kq>>3)*16 + r)*8 + (kq&7)] = f2bf(val);
    } else {
      int idx = (vb - 15676) * 256 + tid;   // < 8192 exact
      int cw = idx >> 9, kp = idx & 511;
      int dt = kp / 96, ch = kp - dt * 96;
      float val = (dt < 5) ? W3e[cw*480 + dt*96 + ch] : 0.f;
      int ks = kp >> 5, kq = kp & 31;
      W3f[ks*512 + ((kq>>3)*16 + cw)*8 + (kq&7)] = f2bf(val);
    }
  }
  grid_barrier(bar, nblk);

  // ================= Phase 2: composed Wc (hi+lo) + biasC =================
  for (int vb = blockIdx.x; vb < 4705; vb += nblk){
    if (vb == 4704){
      if (tid < 128){
        int kpi = 1176 + (tid >> 4), qq = tid & 15;
        int ks = kpi >> 5, kq = kpi & 31;
        int pos = ks*512 + ((kq>>3)*16 + qq)*8 + (kq&7);
        WcfH[pos] = 0; WcfL[pos] = 0;
      }
      for (int qi = 0; qi < 4; ++qi){
        int qq = h*4 + qi;
        float accl = 0.f;
        for (int d23 = 0; d23 < 13; ++d23){
          const float* wrow = W32 + (qq*13 + d23)*272;
#pragma unroll
          for (int j = 0; j < 5; ++j){
            int p = lane + j*64;
            if (p < 272) accl += wrow[p] * b1f[p];
          }
        }
        for (int m = 32; m > 0; m >>= 1) accl += __shfl_xor(accl, m);
        if (lane == 0){
          float ind = 0.f;
          for (int d23 = 0; d23 < 13; ++d23) ind += W32i[qq*13 + d23];
          biasC[qq] = accl + ind;
        }
      }
    } else {
      int wid = vb * 4 + h;              // < 18816 exact
      int qq = wid / 1176, rem = wid - qq * 1176;
      int D = rem / 56, uu = rem - D * 56;
      float accl = 0.f;
      if (uu < 51){
        for (int d1 = 0; d1 < 9; ++d1){
          int d23 = D - d1;
          if (d23 < 0 || d23 >= 13) continue;
          const float* wrow = W32 + (qq*13 + d23)*272;
          const float* w1r  = W1eT + (d1*51 + uu)*272;
#pragma unroll
          for (int j = 0; j < 5; ++j){
            int p = lane + j*64;
            if (p < 272) accl += wrow[p] * w1r[p];
          }
        }
      }
      for (int m = 32; m > 0; m >>= 1) accl += __shfl_xor(accl, m);
      if (lane == 0){
        int kp = D * 56 + uu;
        int ks = kp >> 5, kq = kp & 31;
        int pos = ks*512 + ((kq>>3)*16 + qq)*8 + (kq&7);
        u16 hb = f2bf(accl);
        float hf = __builtin_bit_cast(float, (uint32_t)hb << 16);
        WcfH[pos] = hb;
        WcfL[pos] = f2bf(accl - hf);
      }
    }
  }
  grid_barrier(bar, nblk);

  // ================= Phase 3: fixup + interior (former fused_main) =================
  for (int vb = blockIdx.x; vb < 66 * 16; vb += nblk){
    const int bx = vb % 66;
    const int n  = vb / 66;
    if (bx < 2){
      // -------- boundary fixup (MFMA), t in [0,7) u [T-7,T) --------
      const int e = bx;
      const int base1 = e ? (T_LEN - 14) : 0;
      const int off1 = e ? 0 : 4, off2 = e ? 0 : 2, off3 = e ? 0 : 1;

      for (int i = tid; i < 1140; i += 256){
        if (i < 850)        *reinterpret_cast<u16x8*>(&X1s[i*8]) = (u16x8)0;
        else if (i < 1102)  *reinterpret_cast<u16x8*>(&X2s[(i-850)*8]) = (u16x8)0;
        else                *reinterpret_cast<u16x8*>(&X3s[(i-1102)*8]) = (u16x8)0;
      }
      for (int idx = tid; idx < 25 * 7; idx += 256){
        int r = idx / 7, g = idx - r * 7;
        int t = base1 + r - 4;
        u16x8 v = (u16x8)0;
        if (t >= 0 && t < T_LEN)
          v = *reinterpret_cast<const u16x8*>(&X0[((size_t)n * T_LEN + t) * 56 + g * 8]);
        *reinterpret_cast<u16x8*>(&xs[r * 56 + g * 8]) = v;
      }
      __syncthreads();

      for (int mt = h; mt < 17; mt += 4){
        f32x4 acc = (f32x4){0.f,0.f,0.f,0.f};
        for (int ks = 0; ks < 16; ++ks){
          bf16x8 aF = *reinterpret_cast<const bf16x8*>(&W1f[(ks*17 + mt)*512 + lane*8]);
          int k0 = ks*32 + q*8;
          int dt = k0 / 56, rr = k0 - dt*56;
          bf16x8 bF = *reinterpret_cast<const bf16x8*>(&xs[(l15 + dt)*56 + rr]);
          acc = __builtin_amdgcn_mfma_f32_16x16x32_bf16(aF, bF, acc, 0, 0, 0);
        }
        if (l15 < 14){
          int chb = mt*16 + q*4;
          ushort4 o;
          o.x = f2bf(acc[0] + b1f[chb+0]); o.y = f2bf(acc[1] + b1f[chb+1]);
          o.z = f2bf(acc[2] + b1f[chb+2]); o.w = f2bf(acc[3] + b1f[chb+3]);
          *reinterpret_cast<ushort4*>(&X1s[(l15 + off1)*272 + chb]) = o;
        }
      }
      __syncthreads();

      for (int mt = h; mt < 6; mt += 4){
        f32x4 acc = (f32x4){0.f,0.f,0.f,0.f};
        for (int ks = 0; ks < 78; ++ks){
          bf16x8 aF = *reinterpret_cast<const bf16x8*>(&W2f[(ks*6 + mt)*512 + lane*8]);
          int k0 = ks*32 + q*8;
          int dt = k0 / 272, rr = k0 - dt*272;
          bf16x8 bF = *reinterpret_cast<const bf16x8*>(&X1s[(l15 + dt)*272 + rr]);
          acc = __builtin_amdgcn_mfma_f32_16x16x32_bf16(aF, bF, acc, 0, 0, 0);
        }
        if (l15 < 10){
          int chb = mt*16 + q*4;
          ushort4 o;
          o.x = f2bf(acc[0] + b2f[chb+0]); o.y = f2bf(acc[1] + b2f[chb+1]);
          o.z = f2bf(acc[2] + b2f[chb+2]); o.w = f2bf(acc[3] + b2f[chb+3]);
          *reinterpret_cast<ushort4*>(&X2s[(l15 + off2)*96 + chb]) = o;
        }
      }
      __syncthreads();

      if (h == 0){
        f32x4 acc = (f32x4){0.f,0.f,0.f,0.f};
        for (int ks = 0; ks < 16; ++ks){
          bf16x8 aF = *reinterpret_cast<const bf16x8*>(&W3f[ks*512 + lane*8]);
          int k0 = ks*32 + q*8;
          int dt = k0 / 96, rr = k0 - dt*96;
          bf16x8 bF = *reinterpret_cast<const bf16x8*>(&X2s[(l15 + dt)*96 + rr]);
          acc = __builtin_amdgcn_mfma_f32_16x16x32_bf16(aF, bF, acc, 0, 0, 0);
        }
        if (l15 < 8){
          float v0 = acc[0] + b3f[q*4+0], v1 = acc[1] + b3f[q*4+1];
          float v2 = acc[2] + b3f[q*4+2], v3 = acc[3] + b3f[q*4+3];
          v0 = v0 > 0.f ? v0 : 0.01f*v0; v1 = v1 > 0.f ? v1 : 0.01f*v1;
          v2 = v2 > 0.f ? v2 : 0.01f*v2; v3 = v3 > 0.f ? v3 : 0.01f*v3;
          ushort4 o; o.x = f2bf(v0); o.y = f2bf(v1); o.z = f2bf(v2); o.w = f2bf(v3);
          *reinterpret_cast<ushort4*>(&X3s[(l15 + off3)*16 + q*4]) = o;
        }
      }
      __syncthreads();

      {
        f32x4 acc = (f32x4){0.f,0.f,0.f,0.f};
        for (int ks = 0; ks < 2; ++ks){
          bf16x8 aF = *reinterpret_cast<const bf16x8*>(&W4f[(ks*4 + h)*512 + lane*8]);
          int k0 = ks*32 + q*8;
          int dt2 = k0 >> 4, ch0 = k0 & 15;
          bf16x8 bF = *reinterpret_cast<const bf16x8*>(&X3s[(l15 + dt2)*16 + ch0]);
          acc = __builtin_amdgcn_mfma_f32_16x16x32_bf16(aF, bF, acc, 0, 0, 0);
        }
        if (l15 < 7){
          int chb = h*16 + q*4;
          int t = (e ? (T_LEN - 7) : 0) + l15;
          float v0 = acc[0] + b4f[chb+0], v1 = acc[1] + b4f[chb+1];
          float v2 = acc[2] + b4f[chb+2], v3 = acc[3] + b4f[chb+3];
          v0 = v0 > 0.f ? v0 : 0.01f*v0; v1 = v1 > 0.f ? v1 : 0.01f*v1;
          v2 = v2 > 0.f ? v2 : 0.01f*v2; v3 = v3 > 0.f ? v3 : 0.01f*v3;
          float4 o; o.x = v0; o.y = v1; o.z = v2; o.w = v3;
          *reinterpret_cast<float4*>(&out[((size_t)n * T_LEN + t) * 64 + chb]) = o;
        }
      }
    } else {
      // -------- interior: composed GEMM + stage 4, t in [7, T-7) --------
      const int t0 = (bx - 2) * 32;

      for (int idx = tid; idx < 69 * 7; idx += 256){
        int row = idx / 7, g = idx - row * 7;
        int ts = t0 + row - 18;
        u16x8 v = (u16x8)0;
        if (ts >= 0 && ts < T_LEN)
          v = *reinterpret_cast<const u16x8*>(&X0[((size_t)n * T_LEN + ts) * 56 + g * 8]);
        *reinterpret_cast<u16x8*>(&patch[row * 56 + g * 8]) = v;
      }
      __syncthreads();

      if (h < 3){
        f32x4 a0 = (f32x4){0.f, 0.f, 0.f, 0.f};
        bf16x8 aH[2], aL[2], bF[2];
        const u16* bp0 = patch + (16 * h + l15) * 56;
        auto load3 = [&](int buf, int ks){
          const int k0 = ks * 32 + q * 8;
          const int D = k0 / 56, rr = k0 - D * 56;
          aH[buf] = *reinterpret_cast<const bf16x8*>(WcfH + ks * 512 + lane * 8);
          aL[buf] = *reinterpret_cast<const bf16x8*>(WcfL + ks * 512 + lane * 8);
          bF[buf] = *reinterpret_cast<const bf16x8*>(bp0 + D * 56 + rr);
        };
        load3(0, 0);
        for (int ks = 0; ks < 37; ++ks){
          const int cur = ks & 1;
          if (ks + 1 < 37) load3(cur ^ 1, ks + 1);
          a0 = __builtin_amdgcn_mfma_f32_16x16x32_bf16(aH[cur], bF[cur], a0, 0, 0, 0);
          a0 = __builtin_amdgcn_mfma_f32_16x16x32_bf16(aL[cur], bF[cur], a0, 0, 0, 0);
        }
        const float bc0 = biasC[q*4+0], bc1 = biasC[q*4+1], bc2 = biasC[q*4+2], bc3 = biasC[q*4+3];
        int trow = 16 * h + l15;
        int t = t0 - 8 + trow;
        float v0 = a0[0]+bc0, v1 = a0[1]+bc1, v2 = a0[2]+bc2, v3 = a0[3]+bc3;
        v0 = v0 > 0.f ? v0 : 0.01f*v0; v1 = v1 > 0.f ? v1 : 0.01f*v1;
        v2 = v2 > 0.f ? v2 : 0.01f*v2; v3 = v3 > 0.f ? v3 : 0.01f*v3;
        if (t < 0 || t >= T_LEN){ v0 = v1 = v2 = v3 = 0.f; }
        ushort4 o; o.x = f2bf(v0); o.y = f2bf(v1); o.z = f2bf(v2); o.w = f2bf(v3);
        *reinterpret_cast<ushort4*>(&X3L[trow * 16 + q * 4]) = o;
      }
      __syncthreads();

      {
        f32x4 acc[2];
#pragma unroll
        for (int j = 0; j < 2; ++j) acc[j] = (f32x4){0.f, 0.f, 0.f, 0.f};
        bf16x8 aF[2], bF[2][2];
        auto load4 = [&](int buf, int ks){
          const int k0 = ks * 32 + q * 8;
          const int dt2 = k0 >> 4, ch0 = k0 & 15;
          aF[buf] = *reinterpret_cast<const bf16x8*>(W4f + (ks * 4 + h) * 512 + lane * 8);
#pragma unroll
          for (int j = 0; j < 2; ++j)
            bF[buf][j] = *reinterpret_cast<const bf16x8*>(&X3L[(j * 16 + l15 + dt2 + 7) * 16 + ch0]);
        };
        load4(0, 0); load4(1, 1);
#pragma unroll
        for (int j = 0; j < 2; ++j)
          acc[j] = __builtin_amdgcn_mfma_f32_16x16x32_bf16(aF[0], bF[0][j], acc[j], 0, 0, 0);
#pragma unroll
        for (int j = 0; j < 2; ++j)
          acc[j] = __builtin_amdgcn_mfma_f32_16x16x32_bf16(aF[1], bF[1][j], acc[j], 0, 0, 0);

        const int chb = h * 16 + q * 4;
        const float c0 = b4f[chb+0], c1 = b4f[chb+1], c2 = b4f[chb+2], c3 = b4f[chb+3];
#pragma unroll
        for (int j = 0; j < 2; ++j){
          const int t = t0 + j * 16 + l15;
          float v0 = acc[j][0]+c0, v1 = acc[j][1]+c1, v2 = acc[j][2]+c2, v3 = acc[j][3]+c3;
          v0 = v0 > 0.f ? v0 : 0.01f*v0; v1 = v1 > 0.f ? v1 : 0.01f*v1;
          v2 = v2 > 0.f ? v2 : 0.01f*v2; v3 = v3 > 0.f ? v3 : 0.01f*v3;
          if (t >= 7 && t < T_LEN - 7){
            float4 o; o.x = v0; o.y = v1; o.z = v2; o.w = v3;
            *reinterpret_cast<float4*>(&out[((size_t)n * T_LEN + t) * 64 + chb]) = o;
          }
        }
      }
    }
    __syncthreads();   // protect shared reuse across grid-stride iterations
  }
}

extern "C" void kernel_launch(void* const* d_in, const int* in_sizes, int n_in,
                              void* d_out, int out_size, void* d_ws, size_t ws_size,
                              hipStream_t stream)
{
  const float* poses = (const float*)d_in[0];
  const float* A1  = (const float*)d_in[1];
  const float* A2  = (const float*)d_in[2];
  const float* w1  = (const float*)d_in[3];
  const float* b1  = (const float*)d_in[4];
  const float* g1  = (const float*)d_in[5];
  const float* be1 = (const float*)d_in[6];
  const float* m1  = (const float*)d_in[7];
  const float* v1  = (const float*)d_in[8];
  const float* w2  = (const float*)d_in[9];
  const float* b2  = (const float*)d_in[10];
  const float* g2  = (const float*)d_in[11];
  const float* be2 = (const float*)d_in[12];
  const float* m2  = (const float*)d_in[13];
  const float* v2  = (const float*)d_in[14];
  const float* w3  = (const float*)d_in[15];
  const float* b3  = (const float*)d_in[16];
  const float* g3  = (const float*)d_in[17];
  const float* be3 = (const float*)d_in[18];
  const float* m3  = (const float*)d_in[19];
  const float* v3  = (const float*)d_in[20];
  const float* w4  = (const float*)d_in[21];
  const float* b4  = (const float*)d_in[22];
  const float* g4  = (const float*)d_in[23];
  const float* be4 = (const float*)d_in[24];
  const float* m4  = (const float*)d_in[25];
  const float* v4  = (const float*)d_in[26];

  uint8_t* ws = (uint8_t*)d_ws;
  size_t off = 0;
  auto alloc = [&](size_t bytes) -> void* {
    void* p = ws + off;
    off += (bytes + 255) & ~(size_t)255;
    return p;
  };
  u16*   X0    = (u16*)  alloc((size_t)NB * T_LEN * 56 * 2);
  float* W1e   = (float*)alloc(124848 * 4);
  float* W1eT  = (float*)alloc(124848 * 4);
  float* W2e   = (float*)alloc(235008 * 4);
  float* W2eT  = (float*)alloc(235008 * 4);
  float* W3e   = (float*)alloc(7680 * 4);
  u16*   W4f   = (u16*)  alloc(4096 * 2);
  float* b1f   = (float*)alloc(272 * 4);
  float* b2f   = (float*)alloc(96 * 4);
  float* b3f   = (float*)alloc(16 * 4);
  float* b4f   = (float*)alloc(64 * 4);
  float* W32   = (float*)alloc(208 * 272 * 4);
  float* W32i  = (float*)alloc(208 * 4);
  u16*   WcfH  = (u16*)  alloc(37 * 512 * 2);
  u16*   WcfL  = (u16*)  alloc(37 * 512 * 2);
  float* biasC = (float*)alloc(16 * 4);
  u16*   W1f   = (u16*)  alloc(139264 * 2);
  u16*   W2f   = (u16*)  alloc(239616 * 2);
  u16*   W3f   = (u16*)  alloc(8192 * 2);
  int*   bar   = (int*)  alloc(256);

  hipMemsetAsync(bar, 0, 8, stream);
  hipLaunchKernelGGL(mega, dim3(1024), dim3(256), 0, stream,
                     poses, A1, A2,
                     w1, b1, g1, be1, m1, v1,
                     w2, b2, g2, be2, m2, v2,
                     w3, b3, g3, be3, m3, v3,
                     w4, b4, g4, be4, m4, v4,
                     X0, W1e, W1eT, W2e, W2eT, W3e, W4f,
                     b1f, b2f, b3f, b4f,
                     W32, W32i, WcfH, WcfL, biasC,
                     W1f, W2f, W3f,
                     (float*)d_out, bar);
}

// Round 9
// 222.793 us; speedup vs baseline: 6.4945x; 6.4945x over previous
//
#include <hip/hip_runtime.h>
#include <stdint.h>

typedef unsigned short u16;
typedef __attribute__((ext_vector_type(8))) __bf16 bf16x8;
typedef __attribute__((ext_vector_type(8))) u16 u16x8;
typedef __attribute__((ext_vector_type(4))) float f32x4;

#define T_LEN 2048
#define NB 16

__device__ __forceinline__ u16 f2bf(float f){
  uint32_t x = __builtin_bit_cast(uint32_t, f);
  x += 0x7FFFu + ((x >> 16) & 1u);
  return (u16)(x >> 16);
}

// joint -> (body part, index within part, part length)
__constant__ int c_part[17] = {1,2,3,1,1,4,4,5,5,2,2,3,3,0,0,0,0};
__constant__ int c_pidx[17] = {0,0,0,1,2,0,1,0,1,1,2,1,2,0,1,2,3};
__constant__ int c_plen[17] = {3,3,3,3,3,2,2,2,2,3,3,3,3,4,4,4,4};

// ---- K1 prep_all: everything derivable from raw inputs, one kernel. grid 8972.
// vb ranges:
//  [0,7168)      X0 convert (poses -> bf16 [n][t][56])
//  [7168,7656)   W1 eff weights -> W1eT + W1f fragments
//  [7656,8574)   W2 eff weights -> W2f fragments (235008 exact)
//  [8574,8606)   W3f fragments direct (8192)
//  [8606,8622)   W4f fragments (4096)
//  [8622,8624)   biases b1f/b2f/b3f/b4f (448)
//  [8624,8681)   W1f zero-pad (14416)
//  [8681,8699)   W2f zero-pad (4608)
//  [8699,8971)   W32 direct-from-inputs, one block per p (LDS-staged W2col+W3e)
//  [8971]        W32ind (redundant b2f/b3f in-block)
__launch_bounds__(256)
__global__ void prep_all(
  const float* __restrict__ poses, const float* __restrict__ A1, const float* __restrict__ A2,
  const float* __restrict__ w1, const float* __restrict__ b1, const float* __restrict__ g1,
  const float* __restrict__ be1, const float* __restrict__ m1, const float* __restrict__ v1,
  const float* __restrict__ w2, const float* __restrict__ b2, const float* __restrict__ g2,
  const float* __restrict__ be2, const float* __restrict__ m2, const float* __restrict__ v2,
  const float* __restrict__ w3, const float* __restrict__ b3, const float* __restrict__ g3,
  const float* __restrict__ be3, const float* __restrict__ m3, const float* __restrict__ v3,
  const float* __restrict__ w4, const float* __restrict__ b4, const float* __restrict__ g4,
  const float* __restrict__ be4, const float* __restrict__ m4, const float* __restrict__ v4,
  u16* __restrict__ X0, float* __restrict__ W1eT,
  u16* __restrict__ W1f, u16* __restrict__ W2f, u16* __restrict__ W3f, u16* __restrict__ W4f,
  float* __restrict__ b1f, float* __restrict__ b2f, float* __restrict__ b3f, float* __restrict__ b4f,
  float* __restrict__ W32, float* __restrict__ W32i)
{
  __shared__ float W2L[864];     // [o][d2] for fixed p
  __shared__ float W3L[7680];    // [q][d3][o]
  __shared__ float b2L[96];
  __shared__ float b3L[16];
  __shared__ float s3L[16];

  const int vb  = blockIdx.x;
  const int tid = threadIdx.x;
  const int lane = tid & 63;
  const int h    = tid >> 6;

  if (vb < 7168){
    int e = vb * 256 + tid;
    int row = e / 56, c = e - row * 56;
    u16 v = 0;
    if (c < 51) v = f2bf(poses[row * 51 + c]);
    X0[e] = v;
  } else if (vb < 7656){
    int idx = (vb - 7168) * 256 + tid;
    if (idx < 124848){
      int p = idx / 459, rem = idx - p * 459;
      int d1 = rem / 51, u = rem - d1 * 51;
      int c = p / 17, w = p - c * 17;
      int uj = u / 3, ci = u - uj * 3;
      float val = 0.f;
      for (int kk = 0; kk < 5; ++kk)
        for (int dv = 0; dv < 5; ++dv){
          int v = uj - dv + 2;
          if (v >= 0 && v < 17)
            val += w1[(kk*16 + c)*135 + ci*45 + d1*5 + dv] * A1[kk*289 + v*17 + w];
        }
      val *= g1[p] * rsqrtf(v1[p] + 1e-5f);
      W1eT[(d1*51 + u)*272 + p] = val;
      int kp = d1*56 + u;
      int mt = p >> 4, r = p & 15, ks = kp >> 5, kq = kp & 31;
      W1f[(ks*17 + mt)*512 + ((kq>>3)*16 + r)*8 + (kq&7)] = f2bf(val);
    }
  } else if (vb < 8574){
    int idx = (vb - 7656) * 256 + tid;            // < 235008 exact
    int o = idx / 2448, rem = idx - o * 2448;
    int d2 = rem / 272, pp = rem - d2 * 272;
    int c2 = o / 6, w2i = o - c2 * 6;
    int f = pp / 17, J = pp - f * 17;
    int pt = c_part[J];
    int ci = f * c_plen[J] + c_pidx[J];
    float val = 0.f;
    for (int kk = 0; kk < 5; ++kk)
      for (int dv = 0; dv < 3; ++dv){
        int v = pt - dv + 1;
        if (v >= 0 && v < 6)
          val += w2[(kk*16 + c2)*1728 + ci*27 + d2*3 + dv] * A2[kk*36 + v*6 + w2i];
      }
    val *= g2[o] * rsqrtf(v2[o] + 1e-5f);
    int kp = d2*272 + pp;
    int mt = o >> 4, r = o & 15, ks = kp >> 5, kq = kp & 31;
    W2f[(ks*6 + mt)*512 + ((kq>>3)*16 + r)*8 + (kq&7)] = f2bf(val);
  } else if (vb < 8606){
    int idx = (vb - 8574) * 256 + tid;            // < 8192 exact
    int cw = idx >> 9, kp = idx & 511;
    int dt = kp / 96, ch = kp - dt * 96;
    float val = 0.f;
    if (dt < 5){
      float s = g3[cw] * rsqrtf(v3[cw] + 1e-5f);
      val = s * w3[cw*480 + ch*5 + dt];
    }
    int ks = kp >> 5, kq = kp & 31;
    W3f[ks*512 + ((kq>>3)*16 + cw)*8 + (kq&7)] = f2bf(val);
  } else if (vb < 8622){
    int i2 = (vb - 8606) * 256 + tid;             // < 4096 exact
    int cw = i2 >> 6, kp = i2 & 63;
    int dt = kp >> 4, ch = kp & 15;
    float val = 0.f;
    if (dt < 3){
      float s = g4[cw] * rsqrtf(v4[cw] + 1e-5f);
      val = s * w4[cw*48 + ch*3 + dt];
    }
    int mt = cw >> 4, r = cw & 15, ks = kp >> 5, kq = kp & 31;
    W4f[(ks*4 + mt)*512 + ((kq>>3)*16 + r)*8 + (kq&7)] = f2bf(val);
  } else if (vb < 8624){
    int t2 = (vb - 8622) * 256 + tid;             // < 512, 448 used
    if (t2 < 272){
      int c = t2 / 17, w = t2 - c * 17;
      float beff = 0.f;
      for (int kk = 0; kk < 5; ++kk){
        float rs = 0.f;
        for (int v = 0; v < 17; ++v) rs += A1[kk*289 + v*17 + w];
        beff += b1[kk*16 + c] * rs;
      }
      float s = g1[t2] * rsqrtf(v1[t2] + 1e-5f);
      b1f[t2] = s * (beff - m1[t2]) + be1[t2];
    } else if (t2 < 368){
      int cw = t2 - 272;
      int c = cw / 6, w = cw - c * 6;
      float beff = 0.f;
      for (int kk = 0; kk < 5; ++kk){
        float rs = 0.f;
        for (int v = 0; v < 6; ++v) rs += A2[kk*36 + v*6 + w];
        beff += b2[kk*16 + c] * rs;
      }
      float s = g2[cw] * rsqrtf(v2[cw] + 1e-5f);
      b2f[cw] = s * (beff - m2[cw]) + be2[cw];
    } else if (t2 < 384){
      int o = t2 - 368;
      float s = g3[o] * rsqrtf(v3[o] + 1e-5f);
      b3f[o] = s * (b3[o] - m3[o]) + be3[o];
    } else if (t2 < 448){
      int o = t2 - 384;
      float s = g4[o] * rsqrtf(v4[o] + 1e-5f);
      b4f[o] = s * (b4[o] - m4[o]) + be4[o];
    }
  } else if (vb < 8681){
    int i = (vb - 8624) * 256 + tid;              // < 14416 (W1f pads)
    if (i < 14416){
      int cw = i / 53, j = i - cw * 53;
      int kp = (j < 45) ? ((j/5)*56 + 51 + (j - (j/5)*5)) : (504 + (j - 45));
      int mt = cw >> 4, r = cw & 15, ks = kp >> 5, kq = kp & 31;
      W1f[(ks*17 + mt)*512 + ((kq>>3)*16 + r)*8 + (kq&7)] = 0;
    }
  } else if (vb < 8699){
    int i = (vb - 8681) * 256 + tid;              // < 4608 exact (W2f pads)
    int cw = i / 48, kp = 2448 + (i - cw * 48);
    int mt = cw >> 4, r = cw & 15, ks = kp >> 5, kq = kp & 31;
    W2f[(ks*6 + mt)*512 + ((kq>>3)*16 + r)*8 + (kq&7)] = 0;
  } else if (vb < 8971){
    // ---- W32 direct: one block per p. Stage W2 column + W3e in LDS. ----
    const int p = vb - 8699;
    const int f = p / 17, J = p - f * 17;
    const int pt = c_part[J];
    const int ci = f * c_plen[J] + c_pidx[J];
    for (int t = tid; t < 864; t += 256){
      int o = t / 9, d2 = t - o * 9;
      int c2 = o / 6, w2i = o - c2 * 6;
      float val = 0.f;
      for (int kk = 0; kk < 5; ++kk)
        for (int dv = 0; dv < 3; ++dv){
          int v = pt - dv + 1;
          if (v >= 0 && v < 6)
            val += w2[(kk*16 + c2)*1728 + ci*27 + d2*3 + dv] * A2[kk*36 + v*6 + w2i];
        }
      val *= g2[o] * rsqrtf(v2[o] + 1e-5f);
      W2L[o*9 + d2] = val;
    }
    for (int t = tid; t < 7680; t += 256){
      int qq = t / 480, r = t - qq * 480;
      int d3 = r / 96, o = r - d3 * 96;
      W3L[t] = g3[qq] * rsqrtf(v3[qq] + 1e-5f) * w3[qq*480 + o*5 + d3];
    }
    __syncthreads();
    for (int ob = h; ob < 208; ob += 4){
      int qq = ob / 13, d23 = ob - qq * 13;
      float accl = 0.f;
      for (int d3 = 0; d3 < 5; ++d3){
        int d2 = d23 - d3;
        if (d2 < 0 || d2 >= 9) continue;
#pragma unroll
        for (int j = 0; j < 2; ++j){
          int o = lane + j*64;
          if (o < 96) accl += W3L[qq*480 + d3*96 + o] * W2L[o*9 + d2];
        }
      }
      for (int m = 32; m > 0; m >>= 1) accl += __shfl_xor(accl, m);
      if (lane == 0) W32[ob*272 + p] = accl;
    }
  } else {
    // ---- W32ind: redundant b2f/b3f/s3 in-block. ----
    if (tid < 96){
      int o = tid, c2 = o / 6, w2i = o - c2 * 6;
      float beff = 0.f;
      for (int kk = 0; kk < 5; ++kk){
        float rs = 0.f;
        for (int v = 0; v < 6; ++v) rs += A2[kk*36 + v*6 + w2i];
        beff += b2[kk*16 + c2] * rs;
      }
      float s = g2[o] * rsqrtf(v2[o] + 1e-5f);
      b2L[o] = s * (beff - m2[o]) + be2[o];
    } else if (tid < 112){
      int qq = tid - 96;
      float s = g3[qq] * rsqrtf(v3[qq] + 1e-5f);
      s3L[qq] = s;
      b3L[qq] = s * (b3[qq] - m3[qq]) + be3[qq];
    }
    __syncthreads();
    for (int ob = h; ob < 208; ob += 4){
      int qq = ob / 13, d23 = ob - qq * 13;
      float accl = 0.f;
      int d3 = d23 - 4;
      if (d3 >= 0 && d3 < 5){
#pragma unroll
        for (int j = 0; j < 2; ++j){
          int o = lane + j*64;
          if (o < 96) accl += s3L[qq] * w3[qq*480 + o*5 + d3] * b2L[o];
        }
      }
      for (int m = 32; m > 0; m >>= 1) accl += __shfl_xor(accl, m);
      if (lane == 0){
        if (d23 == 6) accl += b3L[qq];
        W32i[ob] = accl;
      }
    }
  }
}

// ---- K2 prep_Wc: composed Wc hi/lo fragments + biasC. grid 1177.
// Block <1176: 4 waves, each wave = 4 consecutive uu of one (q,D). Block 1176: pad + biasC.
__launch_bounds__(256)
__global__ void prep_Wc(const float* __restrict__ W32, const float* __restrict__ W32i,
                        const float* __restrict__ W1eT, const float* __restrict__ b1f,
                        u16* __restrict__ WcfH, u16* __restrict__ WcfL,
                        float* __restrict__ biasC)
{
  const int tid = threadIdx.x;
  const int lane = tid & 63;
  const int h = tid >> 6;
  if (blockIdx.x == 1176){
    if (tid < 128){
      int kpi = 1176 + (tid >> 4), qq = tid & 15;
      int ks = kpi >> 5, kq = kpi & 31;
      int pos = ks*512 + ((kq>>3)*16 + qq)*8 + (kq&7);
      WcfH[pos] = 0; WcfL[pos] = 0;
    }
    for (int qi = 0; qi < 4; ++qi){
      int qq = h*4 + qi;
      float accl = 0.f;
      for (int d23 = 0; d23 < 13; ++d23){
        const float* wrow = W32 + (qq*13 + d23)*272;
#pragma unroll
        for (int j = 0; j < 5; ++j){
          int p = lane + j*64;
          if (p < 272) accl += wrow[p] * b1f[p];
        }
      }
      for (int m = 32; m > 0; m >>= 1) accl += __shfl_xor(accl, m);
      if (lane == 0){
        float ind = 0.f;
        for (int d23 = 0; d23 < 13; ++d23) ind += W32i[qq*13 + d23];
        biasC[qq] = accl + ind;
      }
    }
    return;
  }
  int g = blockIdx.x * 4 + h;            // < 4704
  int q = g / 294, rem = g - q * 294;
  int D = rem / 14, u4 = (rem - D * 14) * 4;
  float a0=0.f, a1=0.f, a2=0.f, a3=0.f;
  for (int d1 = 0; d1 < 9; ++d1){
    int d23 = D - d1;
    if (d23 < 0 || d23 >= 13) continue;
    const float* wrow = W32 + (q*13 + d23)*272;
    const float* w1b  = W1eT + (d1*51)*272;
#pragma unroll
    for (int j = 0; j < 5; ++j){
      int p = lane + j*64;
      if (p < 272){
        float wr = wrow[p];
        if (u4+0 < 51) a0 += wr * w1b[(u4+0)*272 + p];
        if (u4+1 < 51) a1 += wr * w1b[(u4+1)*272 + p];
        if (u4+2 < 51) a2 += wr * w1b[(u4+2)*272 + p];
        if (u4+3 < 51) a3 += wr * w1b[(u4+3)*272 + p];
      }
    }
  }
  for (int m = 32; m > 0; m >>= 1){
    a0 += __shfl_xor(a0, m); a1 += __shfl_xor(a1, m);
    a2 += __shfl_xor(a2, m); a3 += __shfl_xor(a3, m);
  }
  if (lane == 0){
    float accs[4] = {a0, a1, a2, a3};
#pragma unroll
    for (int mI = 0; mI < 4; ++mI){
      int uu = u4 + mI;
      float a = (uu < 51) ? accs[mI] : 0.f;
      int kp = D*56 + uu;
      int ks = kp >> 5, kq = kp & 31;
      int pos = ks*512 + ((kq>>3)*16 + q)*8 + (kq&7);
      u16 hb = f2bf(a);
      float hf = __builtin_bit_cast(float, (uint32_t)hb << 16);
      WcfH[pos] = hb;
      WcfL[pos] = f2bf(a - hf);
    }
  }
}

// ---- K3 fused_main: grid (66,16), 256 threads. (unchanged from round 7)
__launch_bounds__(256)
__global__ void fused_main(const u16* __restrict__ X0, const u16* __restrict__ WcfH,
                           const u16* __restrict__ WcfL, const float* __restrict__ biasC,
                           const u16* __restrict__ W4f, const float* __restrict__ bias4f,
                           const u16* __restrict__ W1f, const u16* __restrict__ W2f,
                           const u16* __restrict__ W3f,
                           const float* __restrict__ b1f, const float* __restrict__ b2f,
                           const float* __restrict__ b3f,
                           float* __restrict__ out)
{
  __shared__ __align__(16) u16 patch[69 * 56];
  __shared__ __align__(16) u16 X3L[48 * 16];
  __shared__ __align__(16) u16 xs [25 * 56];
  __shared__ __align__(16) u16 X1s[25 * 272];
  __shared__ __align__(16) u16 X2s[21 * 96];
  __shared__ __align__(16) u16 X3s[19 * 16];

  const int n  = blockIdx.y;
  const int tid = threadIdx.x;
  const int lane = tid & 63;
  const int h    = tid >> 6;
  const int q    = lane >> 4;
  const int l15  = lane & 15;

  if (blockIdx.x < 2){
    const int e = blockIdx.x;
    const int base1 = e ? (T_LEN - 14) : 0;
    const int off1 = e ? 0 : 4, off2 = e ? 0 : 2, off3 = e ? 0 : 1;

    for (int i = tid; i < 1140; i += 256){
      if (i < 850)        *reinterpret_cast<u16x8*>(&X1s[i*8]) = (u16x8)0;
      else if (i < 1102)  *reinterpret_cast<u16x8*>(&X2s[(i-850)*8]) = (u16x8)0;
      else                *reinterpret_cast<u16x8*>(&X3s[(i-1102)*8]) = (u16x8)0;
    }
    for (int idx = tid; idx < 25 * 7; idx += 256){
      int r = idx / 7, g = idx - r * 7;
      int t = base1 + r - 4;
      u16x8 v = (u16x8)0;
      if (t >= 0 && t < T_LEN)
        v = *reinterpret_cast<const u16x8*>(&X0[((size_t)n * T_LEN + t) * 56 + g * 8]);
      *reinterpret_cast<u16x8*>(&xs[r * 56 + g * 8]) = v;
    }
    __syncthreads();

    for (int mt = h; mt < 17; mt += 4){
      f32x4 acc = (f32x4){0.f,0.f,0.f,0.f};
      for (int ks = 0; ks < 16; ++ks){
        bf16x8 aF = *reinterpret_cast<const bf16x8*>(&W1f[(ks*17 + mt)*512 + lane*8]);
        int k0 = ks*32 + q*8;
        int dt = k0 / 56, rr = k0 - dt*56;
        bf16x8 bF = *reinterpret_cast<const bf16x8*>(&xs[(l15 + dt)*56 + rr]);
        acc = __builtin_amdgcn_mfma_f32_16x16x32_bf16(aF, bF, acc, 0, 0, 0);
      }
      if (l15 < 14){
        int chb = mt*16 + q*4;
        ushort4 o;
        o.x = f2bf(acc[0] + b1f[chb+0]); o.y = f2bf(acc[1] + b1f[chb+1]);
        o.z = f2bf(acc[2] + b1f[chb+2]); o.w = f2bf(acc[3] + b1f[chb+3]);
        *reinterpret_cast<ushort4*>(&X1s[(l15 + off1)*272 + chb]) = o;
      }
    }
    __syncthreads();

    for (int mt = h; mt < 6; mt += 4){
      f32x4 acc = (f32x4){0.f,0.f,0.f,0.f};
      for (int ks = 0; ks < 78; ++ks){
        bf16x8 aF = *reinterpret_cast<const bf16x8*>(&W2f[(ks*6 + mt)*512 + lane*8]);
        int k0 = ks*32 + q*8;
        int dt = k0 / 272, rr = k0 - dt*272;
        bf16x8 bF = *reinterpret_cast<const bf16x8*>(&X1s[(l15 + dt)*272 + rr]);
        acc = __builtin_amdgcn_mfma_f32_16x16x32_bf16(aF, bF, acc, 0, 0, 0);
      }
      if (l15 < 10){
        int chb = mt*16 + q*4;
        ushort4 o;
        o.x = f2bf(acc[0] + b2f[chb+0]); o.y = f2bf(acc[1] + b2f[chb+1]);
        o.z = f2bf(acc[2] + b2f[chb+2]); o.w = f2bf(acc[3] + b2f[chb+3]);
        *reinterpret_cast<ushort4*>(&X2s[(l15 + off2)*96 + chb]) = o;
      }
    }
    __syncthreads();

    if (h == 0){
      f32x4 acc = (f32x4){0.f,0.f,0.f,0.f};
      for (int ks = 0; ks < 16; ++ks){
        bf16x8 aF = *reinterpret_cast<const bf16x8*>(&W3f[ks*512 + lane*8]);
        int k0 = ks*32 + q*8;
        int dt = k0 / 96, rr = k0 - dt*96;
        bf16x8 bF = *reinterpret_cast<const bf16x8*>(&X2s[(l15 + dt)*96 + rr]);
        acc = __builtin_amdgcn_mfma_f32_16x16x32_bf16(aF, bF, acc, 0, 0, 0);
      }
      if (l15 < 8){
        float v0 = acc[0] + b3f[q*4+0], v1 = acc[1] + b3f[q*4+1];
        float v2 = acc[2] + b3f[q*4+2], v3 = acc[3] + b3f[q*4+3];
        v0 = v0 > 0.f ? v0 : 0.01f*v0; v1 = v1 > 0.f ? v1 : 0.01f*v1;
        v2 = v2 > 0.f ? v2 : 0.01f*v2; v3 = v3 > 0.f ? v3 : 0.01f*v3;
        ushort4 o; o.x = f2bf(v0); o.y = f2bf(v1); o.z = f2bf(v2); o.w = f2bf(v3);
        *reinterpret_cast<ushort4*>(&X3s[(l15 + off3)*16 + q*4]) = o;
      }
    }
    __syncthreads();

    {
      f32x4 acc = (f32x4){0.f,0.f,0.f,0.f};
      for (int ks = 0; ks < 2; ++ks){
        bf16x8 aF = *reinterpret_cast<const bf16x8*>(&W4f[(ks*4 + h)*512 + lane*8]);
        int k0 = ks*32 + q*8;
        int dt2 = k0 >> 4, ch0 = k0 & 15;
        bf16x8 bF = *reinterpret_cast<const bf16x8*>(&X3s[(l15 + dt2)*16 + ch0]);
        acc = __builtin_amdgcn_mfma_f32_16x16x32_bf16(aF, bF, acc, 0, 0, 0);
      }
      if (l15 < 7){
        int chb = h*16 + q*4;
        int t = (e ? (T_LEN - 7) : 0) + l15;
        float v0 = acc[0] + bias4f[chb+0], v1 = acc[1] + bias4f[chb+1];
        float v2 = acc[2] + bias4f[chb+2], v3 = acc[3] + bias4f[chb+3];
        v0 = v0 > 0.f ? v0 : 0.01f*v0; v1 = v1 > 0.f ? v1 : 0.01f*v1;
        v2 = v2 > 0.f ? v2 : 0.01f*v2; v3 = v3 > 0.f ? v3 : 0.01f*v3;
        float4 o; o.x = v0; o.y = v1; o.z = v2; o.w = v3;
        *reinterpret_cast<float4*>(&out[((size_t)n * T_LEN + t) * 64 + chb]) = o;
      }
    }
    return;
  }

  const int t0 = (blockIdx.x - 2) * 32;

  for (int idx = tid; idx < 69 * 7; idx += 256){
    int row = idx / 7, g = idx - row * 7;
    int ts = t0 + row - 18;
    u16x8 v = (u16x8)0;
    if (ts >= 0 && ts < T_LEN)
      v = *reinterpret_cast<const u16x8*>(&X0[((size_t)n * T_LEN + ts) * 56 + g * 8]);
    *reinterpret_cast<u16x8*>(&patch[row * 56 + g * 8]) = v;
  }
  __syncthreads();

  if (h < 3){
    f32x4 a0 = (f32x4){0.f, 0.f, 0.f, 0.f};
    bf16x8 aH[2], aL[2], bF[2];
    const u16* bp0 = patch + (16 * h + l15) * 56;
    auto load3 = [&](int buf, int ks){
      const int k0 = ks * 32 + q * 8;
      const int D = k0 / 56, rr = k0 - D * 56;
      aH[buf] = *reinterpret_cast<const bf16x8*>(WcfH + ks * 512 + lane * 8);
      aL[buf] = *reinterpret_cast<const bf16x8*>(WcfL + ks * 512 + lane * 8);
      bF[buf] = *reinterpret_cast<const bf16x8*>(bp0 + D * 56 + rr);
    };
    load3(0, 0);
    for (int ks = 0; ks < 37; ++ks){
      const int cur = ks & 1;
      if (ks + 1 < 37) load3(cur ^ 1, ks + 1);
      a0 = __builtin_amdgcn_mfma_f32_16x16x32_bf16(aH[cur], bF[cur], a0, 0, 0, 0);
      a0 = __builtin_amdgcn_mfma_f32_16x16x32_bf16(aL[cur], bF[cur], a0, 0, 0, 0);
    }
    const float bc0 = biasC[q*4+0], bc1 = biasC[q*4+1], bc2 = biasC[q*4+2], bc3 = biasC[q*4+3];
    int trow = 16 * h + l15;
    int t = t0 - 8 + trow;
    float v0 = a0[0]+bc0, v1 = a0[1]+bc1, v2 = a0[2]+bc2, v3 = a0[3]+bc3;
    v0 = v0 > 0.f ? v0 : 0.01f*v0; v1 = v1 > 0.f ? v1 : 0.01f*v1;
    v2 = v2 > 0.f ? v2 : 0.01f*v2; v3 = v3 > 0.f ? v3 : 0.01f*v3;
    if (t < 0 || t >= T_LEN){ v0 = v1 = v2 = v3 = 0.f; }
    ushort4 o; o.x = f2bf(v0); o.y = f2bf(v1); o.z = f2bf(v2); o.w = f2bf(v3);
    *reinterpret_cast<ushort4*>(&X3L[trow * 16 + q * 4]) = o;
  }
  __syncthreads();

  {
    f32x4 acc[2];
#pragma unroll
    for (int j = 0; j < 2; ++j) acc[j] = (f32x4){0.f, 0.f, 0.f, 0.f};
    bf16x8 aF[2], bF[2][2];
    auto load4 = [&](int buf, int ks){
      const int k0 = ks * 32 + q * 8;
      const int dt2 = k0 >> 4, ch0 = k0 & 15;
      aF[buf] = *reinterpret_cast<const bf16x8*>(W4f + (ks * 4 + h) * 512 + lane * 8);
#pragma unroll
      for (int j = 0; j < 2; ++j)
        bF[buf][j] = *reinterpret_cast<const bf16x8*>(&X3L[(j * 16 + l15 + dt2 + 7) * 16 + ch0]);
    };
    load4(0, 0); load4(1, 1);
#pragma unroll
    for (int j = 0; j < 2; ++j)
      acc[j] = __builtin_amdgcn_mfma_f32_16x16x32_bf16(aF[0], bF[0][j], acc[j], 0, 0, 0);
#pragma unroll
    for (int j = 0; j < 2; ++j)
      acc[j] = __builtin_amdgcn_mfma_f32_16x16x32_bf16(aF[1], bF[1][j], acc[j], 0, 0, 0);

    const int chb = h * 16 + q * 4;
    const float c0 = bias4f[chb+0], c1 = bias4f[chb+1], c2 = bias4f[chb+2], c3 = bias4f[chb+3];
#pragma unroll
    for (int j = 0; j < 2; ++j){
      const int t = t0 + j * 16 + l15;
      float v0 = acc[j][0]+c0, v1 = acc[j][1]+c1, v2 = acc[j][2]+c2, v3 = acc[j][3]+c3;
      v0 = v0 > 0.f ? v0 : 0.01f*v0; v1 = v1 > 0.f ? v1 : 0.01f*v1;
      v2 = v2 > 0.f ? v2 : 0.01f*v2; v3 = v3 > 0.f ? v3 : 0.01f*v3;
      if (t >= 7 && t < T_LEN - 7){
        float4 o; o.x = v0; o.y = v1; o.z = v2; o.w = v3;
        *reinterpret_cast<float4*>(&out[((size_t)n * T_LEN + t) * 64 + chb]) = o;
      }
    }
  }
}

extern "C" void kernel_launch(void* const* d_in, const int* in_sizes, int n_in,
                              void* d_out, int out_size, void* d_ws, size_t ws_size,
                              hipStream_t stream)
{
  const float* poses = (const float*)d_in[0];
  const float* A1  = (const float*)d_in[1];
  const float* A2  = (const float*)d_in[2];
  const float* w1  = (const float*)d_in[3];
  const float* b1  = (const float*)d_in[4];
  const float* g1  = (const float*)d_in[5];
  const float* be1 = (const float*)d_in[6];
  const float* m1  = (const float*)d_in[7];
  const float* v1  = (const float*)d_in[8];
  const float* w2  = (const float*)d_in[9];
  const float* b2  = (const float*)d_in[10];
  const float* g2  = (const float*)d_in[11];
  const float* be2 = (const float*)d_in[12];
  const float* m2  = (const float*)d_in[13];
  const float* v2  = (const float*)d_in[14];
  const float* w3  = (const float*)d_in[15];
  const float* b3  = (const float*)d_in[16];
  const float* g3  = (const float*)d_in[17];
  const float* be3 = (const float*)d_in[18];
  const float* m3  = (const float*)d_in[19];
  const float* v3  = (const float*)d_in[20];
  const float* w4  = (const float*)d_in[21];
  const float* b4  = (const float*)d_in[22];
  const float* g4  = (const float*)d_in[23];
  const float* be4 = (const float*)d_in[24];
  const float* m4  = (const float*)d_in[25];
  const float* v4  = (const float*)d_in[26];

  uint8_t* ws = (uint8_t*)d_ws;
  size_t off = 0;
  auto alloc = [&](size_t bytes) -> void* {
    void* p = ws + off;
    off += (bytes + 255) & ~(size_t)255;
    return p;
  };
  u16*   X0    = (u16*)  alloc((size_t)NB * T_LEN * 56 * 2);
  float* W1eT  = (float*)alloc(124848 * 4);
  u16*   W1f   = (u16*)  alloc(139264 * 2);
  u16*   W2f   = (u16*)  alloc(239616 * 2);
  u16*   W3f   = (u16*)  alloc(8192 * 2);
  u16*   W4f   = (u16*)  alloc(4096 * 2);
  float* b1f   = (float*)alloc(272 * 4);
  float* b2f   = (float*)alloc(96 * 4);
  float* b3f   = (float*)alloc(16 * 4);
  float* b4f   = (float*)alloc(64 * 4);
  float* W32   = (float*)alloc(208 * 272 * 4);
  float* W32i  = (float*)alloc(208 * 4);
  u16*   WcfH  = (u16*)  alloc(37 * 512 * 2);
  u16*   WcfL  = (u16*)  alloc(37 * 512 * 2);
  float* biasC = (float*)alloc(16 * 4);

  hipLaunchKernelGGL(prep_all, dim3(8972), dim3(256), 0, stream,
                     poses, A1, A2,
                     w1, b1, g1, be1, m1, v1,
                     w2, b2, g2, be2, m2, v2,
                     w3, b3, g3, be3, m3, v3,
                     w4, b4, g4, be4, m4, v4,
                     X0, W1eT, W1f, W2f, W3f, W4f,
                     b1f, b2f, b3f, b4f, W32, W32i);
  hipLaunchKernelGGL(prep_Wc, dim3(1177), dim3(256), 0, stream,
                     W32, W32i, W1eT, b1f, WcfH, WcfL, biasC);
  hipLaunchKernelGGL(fused_main, dim3(66, 16), dim3(256), 0, stream,
                     X0, WcfH, WcfL, biasC, W4f, b4f, W1f, W2f, W3f,
                     b1f, b2f, b3f, (float*)d_out);
}